// Round 17
// baseline (188.872 us; speedup 1.0000x reference)
//
#include <hip/hip_runtime.h>
#include <stdint.h>

#define BATCH 4
#define SEQ 2048
#define NX 1024
#define NHEAD 16
#define HDIM 64
#define NTOK (BATCH * SEQ)   // 8192
#define QKV_LD (3 * NX)      // 3072

typedef __bf16 bf16_t;
typedef __bf16 bf16x8 __attribute__((ext_vector_type(8)));
typedef __bf16 bf16x4 __attribute__((ext_vector_type(4)));
typedef float  f32x4  __attribute__((ext_vector_type(4)));

#define GLOAD_LDS16(g, l) __builtin_amdgcn_global_load_lds( \
    (const __attribute__((address_space(1))) void*)(g),     \
    (__attribute__((address_space(3))) void*)(l), 16, 0, 0)

#define MFMA16(a, b, c) __builtin_amdgcn_mfma_f32_16x16x32_bf16((a), (b), (c), 0, 0, 0)

#define WAIT_VM0_BAR() do { \
    asm volatile("s_waitcnt vmcnt(0)" ::: "memory"); \
    __builtin_amdgcn_s_barrier(); } while (0)

// V-stripe mapping: V(b,h,d,s) lives TRANSPOSED in the V third of qkv:
//   elem = b*SEQ*QKV_LD + ((h*64+d)*2 + (s>>10))*QKV_LD + 2048 + (s&1023)
// Written by the QKV GEMM epilogue, read by attn staging.

// ---------------- merged preprocessing: w_attn^T + w_proj^T + cast(x) --------
// blocks [0,3072): w_attn [1024][3072] -> wab [3072][1024] bf16
// blocks [3072,4096): w_proj [1024][1024] -> wpb [1024][1024] bf16
// blocks [4096,6144): cast x f32 -> xb bf16 (grid-stride over 2M f32x4)
__global__ __launch_bounds__(256) void k_prep(const float* __restrict__ x,
                                              bf16_t* __restrict__ xb,
                                              const float* __restrict__ w_attn,
                                              bf16_t* __restrict__ wab,
                                              const float* __restrict__ w_proj,
                                              bf16_t* __restrict__ wpb) {
  const int blk = blockIdx.x;
  if (blk < 4096) {
    __shared__ float tile[32][33];
    const float* in;
    bf16_t* out;
    int kb, nb, N;
    if (blk < 3072) {
      in = w_attn; out = wab; N = 3 * NX;
      kb = (blk & 31) * 32; nb = (blk >> 5) * 32;
    } else {
      in = w_proj; out = wpb; N = NX;
      kb = ((blk - 3072) & 31) * 32; nb = ((blk - 3072) >> 5) * 32;
    }
    const int tx = threadIdx.x & 31;
    const int ty = (threadIdx.x >> 5) * 4;
#pragma unroll
    for (int i = 0; i < 4; i++)
      tile[ty + i][tx] = in[(size_t)(kb + ty + i) * N + nb + tx];
    __syncthreads();
#pragma unroll
    for (int i = 0; i < 4; i++)
      out[(size_t)(nb + ty + i) * NX + kb + tx] = (bf16_t)tile[tx][ty + i];
  } else {
    const int n4 = NTOK * NX / 4;
    const int stride = 2048 * 256;
    for (int i = (blk - 4096) * 256 + threadIdx.x; i < n4; i += stride) {
      f32x4 v = ((const f32x4*)x)[i];
      bf16x4 o;
      o[0] = (bf16_t)v[0]; o[1] = (bf16_t)v[1];
      o[2] = (bf16_t)v[2]; o[3] = (bf16_t)v[3];
      ((bf16x4*)xb)[i] = o;
    }
  }
}

// ---------------- QKV GEMM: qkv[M][3072] = A[M][K] * Bt^T + bias --------------
// 128x128 tile, BK=32, 4 waves 2x2; double-buffered LDS, issue-early staging.
// V-blocks (n0>=2048) write TRANSPOSED into the qkv V-stripe via LDS.
__global__ __launch_bounds__(256) void k_gemm_qkv(const bf16_t* __restrict__ A,
                                                  const bf16_t* __restrict__ Bt,
                                                  const float* __restrict__ bias,
                                                  bf16_t* __restrict__ qkv,
                                                  int M, int N, int K) {
  __shared__ __align__(16) bf16_t lsPool[2][2][128 * 32];   // 32 KB
  auto* lsA = lsPool[0];
  auto* lsB = lsPool[1];
  const int tid  = threadIdx.x;
  const int lane = tid & 63;
  const int wid  = tid >> 6;
  const int wr   = wid >> 1, wc = wid & 1;
  const int m0 = blockIdx.x * 128, n0 = blockIdx.y * 128;

  const int srow = tid >> 2;
  const int scol = (tid & 3) * 8;
  const bf16_t* Ap = A  + (size_t)(m0 + srow) * K + scol;
  const bf16_t* Bp = Bt + (size_t)(n0 + srow) * K + scol;
  const int wbase = (tid & ~63) * 8;

  f32x4 acc[4][4];
#pragma unroll
  for (int i = 0; i < 4; i++)
#pragma unroll
    for (int j = 0; j < 4; j++) acc[i][j] = (f32x4){0.f, 0.f, 0.f, 0.f};

  const int fr = lane & 15;
  const int kb = (lane >> 4) * 8;

  auto stage = [&](int buf, int k0) {
    GLOAD_LDS16(Ap + k0,                  &lsA[buf][wbase]);
    GLOAD_LDS16(Ap + (size_t)64 * K + k0, &lsA[buf][2048 + wbase]);
    GLOAD_LDS16(Bp + k0,                  &lsB[buf][wbase]);
    GLOAD_LDS16(Bp + (size_t)64 * K + k0, &lsB[buf][2048 + wbase]);
  };

  stage(0, 0);
  __syncthreads();
  const int nk = K >> 5;
  for (int kt = 0; kt < nk; kt++) {
    const int cur = kt & 1;
    if (kt + 1 < nk) stage(cur ^ 1, (kt + 1) * 32);
    bf16x8 af[4], bfr[4];
#pragma unroll
    for (int mf = 0; mf < 4; mf++)
      af[mf] = *(const bf16x8*)&lsA[cur][(wr * 64 + mf * 16 + fr) * 32 + kb];
#pragma unroll
    for (int nf = 0; nf < 4; nf++)
      bfr[nf] = *(const bf16x8*)&lsB[cur][(wc * 64 + nf * 16 + fr) * 32 + kb];
#pragma unroll
    for (int mf = 0; mf < 4; mf++)
#pragma unroll
      for (int nf = 0; nf < 4; nf++)
        acc[mf][nf] = MFMA16(af[mf], bfr[nf], acc[mf][nf]);
    __syncthreads();
  }

  const int col = lane & 15, rb = (lane >> 4) * 4;

  if (n0 < 2 * NX) {
#pragma unroll
    for (int mf = 0; mf < 4; mf++)
#pragma unroll
      for (int nf = 0; nf < 4; nf++) {
        const int gm = m0 + wr * 64 + mf * 16 + rb;
        const int gn = n0 + wc * 64 + nf * 16 + col;
        const float bv = bias[gn];
#pragma unroll
        for (int r = 0; r < 4; r++)
          qkv[(size_t)(gm + r) * QKV_LD + gn] = (bf16_t)(acc[mf][nf][r] + bv);
      }
  } else {
    // V block: transpose via LDS ([64][136] bf16, aliased on lsPool)
    bf16_t* lt = &lsPool[0][0][0];
    const int bb  = m0 >> 11;
    const int m0s = m0 & 2047;
    const int rr = tid >> 4, cc = tid & 15;
#pragma unroll
    for (int p = 0; p < 2; p++) {
      __syncthreads();
      if (wc == p) {
#pragma unroll
        for (int mf = 0; mf < 4; mf++)
#pragma unroll
          for (int nf = 0; nf < 4; nf++) {
            const float bv = bias[n0 + wc * 64 + nf * 16 + col];
            bf16x4 v4;
#pragma unroll
            for (int r = 0; r < 4; r++) v4[r] = (bf16_t)(acc[mf][nf][r] + bv);
            *(bf16x4*)&lt[(nf * 16 + col) * 136 + wr * 64 + mf * 16 + rb] = v4;
          }
      }
      __syncthreads();
      const int hh = ((n0 - 2 * NX) >> 6) + p;
#pragma unroll
      for (int it = 0; it < 4; it++) {
        const int nn = it * 16 + rr;
        bf16x8 v = *(const bf16x8*)&lt[nn * 136 + cc * 8];
        const size_t dst = (size_t)bb * SEQ * QKV_LD +
                           (size_t)((hh * 64 + nn) * 2 + (m0s >> 10)) * QKV_LD +
                           2 * NX + (m0s & 1023) + cc * 8;
        *(bf16x8*)&qkv[dst] = v;
      }
    }
  }
}

// ---------------- GEMM (proj): C[M][N] = A[M][K] * Bt[N][K]^T + bias, f32 out --
__global__ __launch_bounds__(256) void k_gemm_bt(const bf16_t* __restrict__ A,
                                                 const bf16_t* __restrict__ Bt,
                                                 const float* __restrict__ bias,
                                                 float* __restrict__ Cout,
                                                 int M, int N, int K) {
  __shared__ __align__(16) bf16_t lsA[2][128 * 32];
  __shared__ __align__(16) bf16_t lsB[2][128 * 32];
  const int tid  = threadIdx.x;
  const int lane = tid & 63;
  const int wid  = tid >> 6;
  const int wr   = wid >> 1, wc = wid & 1;
  const int m0 = blockIdx.x * 128, n0 = blockIdx.y * 128;

  const int srow = tid >> 2;
  const int scol = (tid & 3) * 8;
  const bf16_t* Ap = A  + (size_t)(m0 + srow) * K + scol;
  const bf16_t* Bp = Bt + (size_t)(n0 + srow) * K + scol;
  const int wbase = (tid & ~63) * 8;

  f32x4 acc[4][4];
#pragma unroll
  for (int i = 0; i < 4; i++)
#pragma unroll
    for (int j = 0; j < 4; j++) acc[i][j] = (f32x4){0.f, 0.f, 0.f, 0.f};

  const int fr = lane & 15;
  const int kb = (lane >> 4) * 8;

  auto stage = [&](int buf, int k0) {
    GLOAD_LDS16(Ap + k0,                  &lsA[buf][wbase]);
    GLOAD_LDS16(Ap + (size_t)64 * K + k0, &lsA[buf][2048 + wbase]);
    GLOAD_LDS16(Bp + k0,                  &lsB[buf][wbase]);
    GLOAD_LDS16(Bp + (size_t)64 * K + k0, &lsB[buf][2048 + wbase]);
  };

  stage(0, 0);
  __syncthreads();
  const int nk = K >> 5;
  for (int kt = 0; kt < nk; kt++) {
    const int cur = kt & 1;
    if (kt + 1 < nk) stage(cur ^ 1, (kt + 1) * 32);
    bf16x8 af[4], bfr[4];
#pragma unroll
    for (int mf = 0; mf < 4; mf++)
      af[mf] = *(const bf16x8*)&lsA[cur][(wr * 64 + mf * 16 + fr) * 32 + kb];
#pragma unroll
    for (int nf = 0; nf < 4; nf++)
      bfr[nf] = *(const bf16x8*)&lsB[cur][(wc * 64 + nf * 16 + fr) * 32 + kb];
#pragma unroll
    for (int mf = 0; mf < 4; mf++)
#pragma unroll
      for (int nf = 0; nf < 4; nf++)
        acc[mf][nf] = MFMA16(af[mf], bfr[nf], acc[mf][nf]);
    __syncthreads();
  }

  const int col = lane & 15, rb = (lane >> 4) * 4;
#pragma unroll
  for (int mf = 0; mf < 4; mf++) {
#pragma unroll
    for (int nf = 0; nf < 4; nf++) {
      const int gm = m0 + wr * 64 + mf * 16 + rb;
      const int gn = n0 + wc * 64 + nf * 16 + col;
      const float bv = bias[gn];
#pragma unroll
      for (int r = 0; r < 4; r++)
        Cout[(size_t)(gm + r) * N + gn] = acc[mf][nf][r] + bv;
    }
  }
}

// ---------------- causal flash attention, KVBLK=128 (r15 best + V-swz fix) ----
// 4 waves/block, 64 q-rows/wave, two 64-kv halves per barrier interval,
// 2-buffer LDS, issue-next-stage-first. Swapped QK^T + permuted K rows -> P
// feeds PV with 0 shuffles. No-max softmax; l via MFMA(pa, ones) -> 1/l is
// lane-local. No s_setprio. V swizzle now folds row bit3 into the XOR:
// S_V(row) = (row ^ (row>>3)) & 7 -- r14's row&7 ignored bit3, so lanes fr and
// fr+8 shared a bank group every V read (1.08M conflict cycles/dispatch).
__global__ __launch_bounds__(256, 2) void k_attn(const bf16_t* __restrict__ qkv,
                                                 bf16_t* __restrict__ attout) {
  __shared__ __align__(16) bf16_t lsK[2][128 * 64];   // [kv 128][d 64]
  __shared__ __align__(16) bf16_t lsV[2][64 * 128];   // [d 64][kv 128]
  const int tid = threadIdx.x, lane = tid & 63, w = tid >> 6;
  const int blk = blockIdx.x;
  const int xcd = blk & 7, idx = blk >> 3;
  const int bh  = xcd * 8 + (idx & 7);
  const int qsb = 7 - (idx >> 3);
  const int b = bh >> 4, h = bh & 15;
  const bf16_t* Qb = qkv + (size_t)b * SEQ * QKV_LD + h * HDIM;
  const bf16_t* Kb = Qb + NX;
  const bf16_t* Vs = qkv + (size_t)b * SEQ * QKV_LD + 2 * NX;  // V-stripe base

  const int fr = lane & 15, g2 = lane >> 4;
  const int kb8 = g2 * 8;
  const int permA = (fr & 3) + 8 * (fr >> 2);

  auto stage = [&](int buf, int kv0) {
#pragma unroll
    for (int s = 0; s < 4; s++) {
      const int i = w * 256 + s * 64 + lane;
      const int rowk = i >> 3, slotk = i & 7;
      const int sk = (rowk & 3) | (((rowk >> 3) & 1) << 2);
      GLOAD_LDS16(Kb + (size_t)(kv0 + rowk) * QKV_LD + ((slotk ^ sk) << 3),
                  &lsK[buf][(w * 256 + s * 64) * 8]);
      const int rowv = i >> 4, slotv = i & 15;
      GLOAD_LDS16(Vs + (size_t)((h * 64 + rowv) * 2 + (kv0 >> 10)) * QKV_LD +
                      (kv0 & 1023) +
                      (((slotv & 8) | ((slotv ^ rowv ^ (rowv >> 3)) & 7)) << 3),
                  &lsV[buf][(w * 256 + s * 64) * 8]);
    }
  };

  const int wb = qsb * 256 + w * 64;   // wave's 64 q-rows [wb, wb+64)
  const int nst = qsb * 2 + 2;         // 128-kv steps

  bf16x8 bq[4][2];
#pragma unroll
  for (int g = 0; g < 4; g++)
#pragma unroll
    for (int kf = 0; kf < 2; kf++) {
      bf16x8 t = *(const bf16x8*)&Qb[(size_t)(wb + g * 16 + fr) * QKV_LD + kf * 32 + kb8];
#pragma unroll
      for (int jj = 0; jj < 8; jj++) t[jj] = (bf16_t)((float)t[jj] * 0.1803368801f);
      bq[g][kf] = t;
    }

  bf16x8 ones;
#pragma unroll
  for (int jj = 0; jj < 8; jj++) ones[jj] = (bf16_t)1.0f;

  f32x4 l_acc[4];
  f32x4 o[4][4];
#pragma unroll
  for (int g = 0; g < 4; g++) {
    l_acc[g] = (f32x4){0.f, 0.f, 0.f, 0.f};
#pragma unroll
    for (int d = 0; d < 4; d++) o[g][d] = (f32x4){0.f, 0.f, 0.f, 0.f};
  }

  stage(0, 0);
  WAIT_VM0_BAR();

  for (int st = 0; st < nst; st++) {
    const int kv0 = st * 128;
    const int cur = st & 1;
    if (st + 1 < nst) stage(cur ^ 1, kv0 + 128);   // issue next-tile loads first
    if (kv0 <= wb) {
#pragma unroll
      for (int h2 = 0; h2 < 2; h2++) {
        const int kvh = kv0 + h2 * 64;
        if (kvh <= wb) {
          // K frags for this 64-half: [sub][A/B][kf]
          bf16x8 ak[2][2][2];
#pragma unroll
          for (int sub = 0; sub < 2; sub++)
#pragma unroll
            for (int ab = 0; ab < 2; ab++)
#pragma unroll
              for (int kf = 0; kf < 2; kf++) {
                const int row = h2 * 64 + sub * 32 + ab * 4 + permA;
                const int sk = (row & 3) | (((row >> 3) & 1) << 2);
                const int c = kf * 4 + g2;
                ak[sub][ab][kf] = *(const bf16x8*)&lsK[cur][row * 64 + ((c ^ sk) << 3)];
              }
          // V frags: [df][kv-quarter within half]
          bf16x8 vbf[4][2];
#pragma unroll
          for (int df = 0; df < 4; df++)
#pragma unroll
            for (int hh = 0; hh < 2; hh++) {
              const int row = df * 16 + fr;
              const int slot = h2 * 8 + (((hh * 4 + g2) ^ row ^ (row >> 3)) & 7);
              vbf[df][hh] = *(const bf16x8*)&lsV[cur][row * 128 + (slot << 3)];
            }
          const int masked = (kvh == wb);
#pragma unroll
          for (int g = 0; g < 4; g++) {
            f32x4 sAB[2][2];
#pragma unroll
            for (int sub = 0; sub < 2; sub++)
#pragma unroll
              for (int ab = 0; ab < 2; ab++) {
                f32x4 s0 = (f32x4){0.f, 0.f, 0.f, 0.f};
                s0 = MFMA16(ak[sub][ab][0], bq[g][0], s0);
                s0 = MFMA16(ak[sub][ab][1], bq[g][1], s0);
                sAB[sub][ab] = s0;
              }
            float sv[16];
#pragma unroll
            for (int sub = 0; sub < 2; sub++)
#pragma unroll
              for (int r = 0; r < 4; r++) {
                sv[sub * 8 + r]     = sAB[sub][0][r];
                sv[sub * 8 + 4 + r] = sAB[sub][1][r];
              }
            if (masked) {
              const int q_abs = wb + g * 16 + fr;
#pragma unroll
              for (int sub = 0; sub < 2; sub++)
#pragma unroll
                for (int r = 0; r < 4; r++) {
                  if (kvh + sub * 32 + g2 * 8 + r     > q_abs) sv[sub * 8 + r]     = -1e30f;
                  if (kvh + sub * 32 + g2 * 8 + 4 + r > q_abs) sv[sub * 8 + 4 + r] = -1e30f;
                }
            }
            bf16_t pb[16];
#pragma unroll
            for (int jj = 0; jj < 16; jj++)
              pb[jj] = (bf16_t)exp2f(sv[jj]);   // no max; no VALU sum (l via MFMA)
            bf16x8 pa0, pa1;
#pragma unroll
            for (int jj = 0; jj < 8; jj++) { pa0[jj] = pb[jj]; pa1[jj] = pb[8 + jj]; }
#pragma unroll
            for (int df = 0; df < 4; df++) {
              o[g][df] = MFMA16(pa0, vbf[df][0], o[g][df]);
              o[g][df] = MFMA16(pa1, vbf[df][1], o[g][df]);
            }
            l_acc[g] = MFMA16(pa0, ones, l_acc[g]);
            l_acc[g] = MFMA16(pa1, ones, l_acc[g]);
          }
        }
      }
    }
    if (st + 1 < nst) WAIT_VM0_BAR();   // next tile landed; buffer safe to swap
  }

  // epilogue: 1/l is lane-local (l_acc rows == o rows); no shuffles
#pragma unroll
  for (int g = 0; g < 4; g++) {
#pragma unroll
    for (int r = 0; r < 4; r++) {
      const float iv = 1.f / l_acc[g][r];
      const int tok = b * SEQ + wb + g * 16 + g2 * 4 + r;
#pragma unroll
      for (int df = 0; df < 4; df++)
        attout[(size_t)tok * NX + h * HDIM + df * 16 + fr] = (bf16_t)(o[g][df][r] * iv);
    }
  }
}

// ---------------- launch ----------------
extern "C" void kernel_launch(void* const* d_in, const int* in_sizes, int n_in,
                              void* d_out, int out_size, void* d_ws, size_t ws_size,
                              hipStream_t stream) {
  const float* x      = (const float*)d_in[0];
  const float* w_attn = (const float*)d_in[1];
  const float* b_attn = (const float*)d_in[2];
  const float* w_proj = (const float*)d_in[3];
  const float* b_proj = (const float*)d_in[4];

  char* ws = (char*)d_ws;
  bf16_t* xb  = (bf16_t*)ws;                   // [0,16) MiB, reused as att
  bf16_t* qkv = (bf16_t*)(ws + (16u << 20));   // [16,64) MiB (V third = vt stripe)
  bf16_t* wab = (bf16_t*)(ws + (64u << 20));   // [64,70) MiB, dead after QKV GEMM
  bf16_t* wpb = (bf16_t*)(ws + (70u << 20));   // [70,72) MiB
  bf16_t* att = xb;

  k_prep<<<6144, 256, 0, stream>>>(x, xb, w_attn, wab, w_proj, wpb);
  k_gemm_qkv<<<dim3(NTOK / 128, (3 * NX) / 128), 256, 0, stream>>>(
      xb, wab, b_attn, qkv, NTOK, 3 * NX, NX);
  // xb and wab dead from here; V already transposed into the qkv stripe
  k_attn<<<BATCH * NHEAD * 8, 256, 0, stream>>>(qkv, att);
  k_gemm_bt<<<dim3(NTOK / 128, NX / 128), 256, 0, stream>>>(
      att, wpb, b_proj, (float*)d_out, NTOK, NX, NX);
}

// Round 18
// 177.634 us; speedup vs baseline: 1.0633x; 1.0633x over previous
//
#include <hip/hip_runtime.h>
#include <stdint.h>

#define BATCH 4
#define SEQ 2048
#define NX 1024
#define NHEAD 16
#define HDIM 64
#define NTOK (BATCH * SEQ)   // 8192
#define QKV_LD (3 * NX)      // 3072

typedef __bf16 bf16_t;
typedef __bf16 bf16x8 __attribute__((ext_vector_type(8)));
typedef __bf16 bf16x4 __attribute__((ext_vector_type(4)));
typedef float  f32x4  __attribute__((ext_vector_type(4)));

#define GLOAD_LDS16(g, l) __builtin_amdgcn_global_load_lds( \
    (const __attribute__((address_space(1))) void*)(g),     \
    (__attribute__((address_space(3))) void*)(l), 16, 0, 0)

#define MFMA16(a, b, c) __builtin_amdgcn_mfma_f32_16x16x32_bf16((a), (b), (c), 0, 0, 0)

#define WAIT_VM0_BAR() do { \
    asm volatile("s_waitcnt vmcnt(0)" ::: "memory"); \
    __builtin_amdgcn_s_barrier(); } while (0)

// V-stripe mapping: V(b,h,d,s) lives TRANSPOSED in the V third of qkv:
//   elem = b*SEQ*QKV_LD + ((h*64+d)*2 + (s>>10))*QKV_LD + 2048 + (s&1023)
// Written by the QKV GEMM epilogue, read by attn staging.

// ---------------- merged preprocessing: w_attn^T + w_proj^T + cast(x) --------
// blocks [0,3072): w_attn [1024][3072] -> wab [3072][1024] bf16
// blocks [3072,4096): w_proj [1024][1024] -> wpb [1024][1024] bf16
// blocks [4096,6144): cast x f32 -> xb bf16 (grid-stride over 2M f32x4)
__global__ __launch_bounds__(256) void k_prep(const float* __restrict__ x,
                                              bf16_t* __restrict__ xb,
                                              const float* __restrict__ w_attn,
                                              bf16_t* __restrict__ wab,
                                              const float* __restrict__ w_proj,
                                              bf16_t* __restrict__ wpb) {
  const int blk = blockIdx.x;
  if (blk < 4096) {
    __shared__ float tile[32][33];
    const float* in;
    bf16_t* out;
    int kb, nb, N;
    if (blk < 3072) {
      in = w_attn; out = wab; N = 3 * NX;
      kb = (blk & 31) * 32; nb = (blk >> 5) * 32;
    } else {
      in = w_proj; out = wpb; N = NX;
      kb = ((blk - 3072) & 31) * 32; nb = ((blk - 3072) >> 5) * 32;
    }
    const int tx = threadIdx.x & 31;
    const int ty = (threadIdx.x >> 5) * 4;
#pragma unroll
    for (int i = 0; i < 4; i++)
      tile[ty + i][tx] = in[(size_t)(kb + ty + i) * N + nb + tx];
    __syncthreads();
#pragma unroll
    for (int i = 0; i < 4; i++)
      out[(size_t)(nb + ty + i) * NX + kb + tx] = (bf16_t)tile[tx][ty + i];
  } else {
    const int n4 = NTOK * NX / 4;
    const int stride = 2048 * 256;
    for (int i = (blk - 4096) * 256 + threadIdx.x; i < n4; i += stride) {
      f32x4 v = ((const f32x4*)x)[i];
      bf16x4 o;
      o[0] = (bf16_t)v[0]; o[1] = (bf16_t)v[1];
      o[2] = (bf16_t)v[2]; o[3] = (bf16_t)v[3];
      ((bf16x4*)xb)[i] = o;
    }
  }
}

// ---------------- QKV GEMM: qkv[M][3072] = A[M][K] * Bt^T + bias --------------
// 128x128 tile, BK=32, 4 waves 2x2; double-buffered LDS, issue-early staging.
// V-blocks (n0>=2048) write TRANSPOSED into the qkv V-stripe via LDS.
__global__ __launch_bounds__(256) void k_gemm_qkv(const bf16_t* __restrict__ A,
                                                  const bf16_t* __restrict__ Bt,
                                                  const float* __restrict__ bias,
                                                  bf16_t* __restrict__ qkv,
                                                  int M, int N, int K) {
  __shared__ __align__(16) bf16_t lsPool[2][2][128 * 32];   // 32 KB
  auto* lsA = lsPool[0];
  auto* lsB = lsPool[1];
  const int tid  = threadIdx.x;
  const int lane = tid & 63;
  const int wid  = tid >> 6;
  const int wr   = wid >> 1, wc = wid & 1;
  const int m0 = blockIdx.x * 128, n0 = blockIdx.y * 128;

  const int srow = tid >> 2;
  const int scol = (tid & 3) * 8;
  const bf16_t* Ap = A  + (size_t)(m0 + srow) * K + scol;
  const bf16_t* Bp = Bt + (size_t)(n0 + srow) * K + scol;
  const int wbase = (tid & ~63) * 8;

  f32x4 acc[4][4];
#pragma unroll
  for (int i = 0; i < 4; i++)
#pragma unroll
    for (int j = 0; j < 4; j++) acc[i][j] = (f32x4){0.f, 0.f, 0.f, 0.f};

  const int fr = lane & 15;
  const int kb = (lane >> 4) * 8;

  auto stage = [&](int buf, int k0) {
    GLOAD_LDS16(Ap + k0,                  &lsA[buf][wbase]);
    GLOAD_LDS16(Ap + (size_t)64 * K + k0, &lsA[buf][2048 + wbase]);
    GLOAD_LDS16(Bp + k0,                  &lsB[buf][wbase]);
    GLOAD_LDS16(Bp + (size_t)64 * K + k0, &lsB[buf][2048 + wbase]);
  };

  stage(0, 0);
  __syncthreads();
  const int nk = K >> 5;
  for (int kt = 0; kt < nk; kt++) {
    const int cur = kt & 1;
    if (kt + 1 < nk) stage(cur ^ 1, (kt + 1) * 32);
    bf16x8 af[4], bfr[4];
#pragma unroll
    for (int mf = 0; mf < 4; mf++)
      af[mf] = *(const bf16x8*)&lsA[cur][(wr * 64 + mf * 16 + fr) * 32 + kb];
#pragma unroll
    for (int nf = 0; nf < 4; nf++)
      bfr[nf] = *(const bf16x8*)&lsB[cur][(wc * 64 + nf * 16 + fr) * 32 + kb];
#pragma unroll
    for (int mf = 0; mf < 4; mf++)
#pragma unroll
      for (int nf = 0; nf < 4; nf++)
        acc[mf][nf] = MFMA16(af[mf], bfr[nf], acc[mf][nf]);
    __syncthreads();
  }

  const int col = lane & 15, rb = (lane >> 4) * 4;

  if (n0 < 2 * NX) {
#pragma unroll
    for (int mf = 0; mf < 4; mf++)
#pragma unroll
      for (int nf = 0; nf < 4; nf++) {
        const int gm = m0 + wr * 64 + mf * 16 + rb;
        const int gn = n0 + wc * 64 + nf * 16 + col;
        const float bv = bias[gn];
#pragma unroll
        for (int r = 0; r < 4; r++)
          qkv[(size_t)(gm + r) * QKV_LD + gn] = (bf16_t)(acc[mf][nf][r] + bv);
      }
  } else {
    // V block: transpose via LDS ([64][136] bf16, aliased on lsPool)
    bf16_t* lt = &lsPool[0][0][0];
    const int bb  = m0 >> 11;
    const int m0s = m0 & 2047;
    const int rr = tid >> 4, cc = tid & 15;
#pragma unroll
    for (int p = 0; p < 2; p++) {
      __syncthreads();
      if (wc == p) {
#pragma unroll
        for (int mf = 0; mf < 4; mf++)
#pragma unroll
          for (int nf = 0; nf < 4; nf++) {
            const float bv = bias[n0 + wc * 64 + nf * 16 + col];
            bf16x4 v4;
#pragma unroll
            for (int r = 0; r < 4; r++) v4[r] = (bf16_t)(acc[mf][nf][r] + bv);
            *(bf16x4*)&lt[(nf * 16 + col) * 136 + wr * 64 + mf * 16 + rb] = v4;
          }
      }
      __syncthreads();
      const int hh = ((n0 - 2 * NX) >> 6) + p;
#pragma unroll
      for (int it = 0; it < 4; it++) {
        const int nn = it * 16 + rr;
        bf16x8 v = *(const bf16x8*)&lt[nn * 136 + cc * 8];
        const size_t dst = (size_t)bb * SEQ * QKV_LD +
                           (size_t)((hh * 64 + nn) * 2 + (m0s >> 10)) * QKV_LD +
                           2 * NX + (m0s & 1023) + cc * 8;
        *(bf16x8*)&qkv[dst] = v;
      }
    }
  }
}

// ---------------- GEMM (proj): C[M][N] = A[M][K] * Bt[N][K]^T + bias, f32 out --
__global__ __launch_bounds__(256) void k_gemm_bt(const bf16_t* __restrict__ A,
                                                 const bf16_t* __restrict__ Bt,
                                                 const float* __restrict__ bias,
                                                 float* __restrict__ Cout,
                                                 int M, int N, int K) {
  __shared__ __align__(16) bf16_t lsA[2][128 * 32];
  __shared__ __align__(16) bf16_t lsB[2][128 * 32];
  const int tid  = threadIdx.x;
  const int lane = tid & 63;
  const int wid  = tid >> 6;
  const int wr   = wid >> 1, wc = wid & 1;
  const int m0 = blockIdx.x * 128, n0 = blockIdx.y * 128;

  const int srow = tid >> 2;
  const int scol = (tid & 3) * 8;
  const bf16_t* Ap = A  + (size_t)(m0 + srow) * K + scol;
  const bf16_t* Bp = Bt + (size_t)(n0 + srow) * K + scol;
  const int wbase = (tid & ~63) * 8;

  f32x4 acc[4][4];
#pragma unroll
  for (int i = 0; i < 4; i++)
#pragma unroll
    for (int j = 0; j < 4; j++) acc[i][j] = (f32x4){0.f, 0.f, 0.f, 0.f};

  const int fr = lane & 15;
  const int kb = (lane >> 4) * 8;

  auto stage = [&](int buf, int k0) {
    GLOAD_LDS16(Ap + k0,                  &lsA[buf][wbase]);
    GLOAD_LDS16(Ap + (size_t)64 * K + k0, &lsA[buf][2048 + wbase]);
    GLOAD_LDS16(Bp + k0,                  &lsB[buf][wbase]);
    GLOAD_LDS16(Bp + (size_t)64 * K + k0, &lsB[buf][2048 + wbase]);
  };

  stage(0, 0);
  __syncthreads();
  const int nk = K >> 5;
  for (int kt = 0; kt < nk; kt++) {
    const int cur = kt & 1;
    if (kt + 1 < nk) stage(cur ^ 1, (kt + 1) * 32);
    bf16x8 af[4], bfr[4];
#pragma unroll
    for (int mf = 0; mf < 4; mf++)
      af[mf] = *(const bf16x8*)&lsA[cur][(wr * 64 + mf * 16 + fr) * 32 + kb];
#pragma unroll
    for (int nf = 0; nf < 4; nf++)
      bfr[nf] = *(const bf16x8*)&lsB[cur][(wc * 64 + nf * 16 + fr) * 32 + kb];
#pragma unroll
    for (int mf = 0; mf < 4; mf++)
#pragma unroll
      for (int nf = 0; nf < 4; nf++)
        acc[mf][nf] = MFMA16(af[mf], bfr[nf], acc[mf][nf]);
    __syncthreads();
  }

  const int col = lane & 15, rb = (lane >> 4) * 4;
#pragma unroll
  for (int mf = 0; mf < 4; mf++) {
#pragma unroll
    for (int nf = 0; nf < 4; nf++) {
      const int gm = m0 + wr * 64 + mf * 16 + rb;
      const int gn = n0 + wc * 64 + nf * 16 + col;
      const float bv = bias[gn];
#pragma unroll
      for (int r = 0; r < 4; r++)
        Cout[(size_t)(gm + r) * N + gn] = acc[mf][nf][r] + bv;
    }
  }
}

// ---------------- causal flash attention, KVBLK=128 (r16 best: 77.0 us) -------
// 4 waves/block, 64 q-rows/wave, two 64-kv halves per barrier interval,
// 2-buffer LDS, issue-next-stage-first. Swapped QK^T + permuted K rows -> P
// feeds PV with 0 shuffles. No-max softmax; l via MFMA(pa, ones) -> 1/l is
// lane-local. No s_setprio. V swizzle S_V(row)=row&7 (r17's bit3-fold probe
// left conflicts EXACTLY unchanged -> V reads are not the conflict source,
// and the altered global pattern cost -13.5 us; reverted).
__global__ __launch_bounds__(256, 2) void k_attn(const bf16_t* __restrict__ qkv,
                                                 bf16_t* __restrict__ attout) {
  __shared__ __align__(16) bf16_t lsK[2][128 * 64];   // [kv 128][d 64]
  __shared__ __align__(16) bf16_t lsV[2][64 * 128];   // [d 64][kv 128]
  const int tid = threadIdx.x, lane = tid & 63, w = tid >> 6;
  const int blk = blockIdx.x;
  const int xcd = blk & 7, idx = blk >> 3;
  const int bh  = xcd * 8 + (idx & 7);
  const int qsb = 7 - (idx >> 3);
  const int b = bh >> 4, h = bh & 15;
  const bf16_t* Qb = qkv + (size_t)b * SEQ * QKV_LD + h * HDIM;
  const bf16_t* Kb = Qb + NX;
  const bf16_t* Vs = qkv + (size_t)b * SEQ * QKV_LD + 2 * NX;  // V-stripe base

  const int fr = lane & 15, g2 = lane >> 4;
  const int kb8 = g2 * 8;
  const int permA = (fr & 3) + 8 * (fr >> 2);

  auto stage = [&](int buf, int kv0) {
#pragma unroll
    for (int s = 0; s < 4; s++) {
      const int i = w * 256 + s * 64 + lane;
      const int rowk = i >> 3, slotk = i & 7;
      const int sk = (rowk & 3) | (((rowk >> 3) & 1) << 2);
      GLOAD_LDS16(Kb + (size_t)(kv0 + rowk) * QKV_LD + ((slotk ^ sk) << 3),
                  &lsK[buf][(w * 256 + s * 64) * 8]);
      const int rowv = i >> 4, slotv = i & 15;
      GLOAD_LDS16(Vs + (size_t)((h * 64 + rowv) * 2 + (kv0 >> 10)) * QKV_LD +
                      (kv0 & 1023) + (((slotv & 8) | ((slotv ^ rowv) & 7)) << 3),
                  &lsV[buf][(w * 256 + s * 64) * 8]);
    }
  };

  const int wb = qsb * 256 + w * 64;   // wave's 64 q-rows [wb, wb+64)
  const int nst = qsb * 2 + 2;         // 128-kv steps

  bf16x8 bq[4][2];
#pragma unroll
  for (int g = 0; g < 4; g++)
#pragma unroll
    for (int kf = 0; kf < 2; kf++) {
      bf16x8 t = *(const bf16x8*)&Qb[(size_t)(wb + g * 16 + fr) * QKV_LD + kf * 32 + kb8];
#pragma unroll
      for (int jj = 0; jj < 8; jj++) t[jj] = (bf16_t)((float)t[jj] * 0.1803368801f);
      bq[g][kf] = t;
    }

  bf16x8 ones;
#pragma unroll
  for (int jj = 0; jj < 8; jj++) ones[jj] = (bf16_t)1.0f;

  f32x4 l_acc[4];
  f32x4 o[4][4];
#pragma unroll
  for (int g = 0; g < 4; g++) {
    l_acc[g] = (f32x4){0.f, 0.f, 0.f, 0.f};
#pragma unroll
    for (int d = 0; d < 4; d++) o[g][d] = (f32x4){0.f, 0.f, 0.f, 0.f};
  }

  stage(0, 0);
  WAIT_VM0_BAR();

  for (int st = 0; st < nst; st++) {
    const int kv0 = st * 128;
    const int cur = st & 1;
    if (st + 1 < nst) stage(cur ^ 1, kv0 + 128);   // issue next-tile loads first
    if (kv0 <= wb) {
#pragma unroll
      for (int h2 = 0; h2 < 2; h2++) {
        const int kvh = kv0 + h2 * 64;
        if (kvh <= wb) {
          // K frags for this 64-half: [sub][A/B][kf]
          bf16x8 ak[2][2][2];
#pragma unroll
          for (int sub = 0; sub < 2; sub++)
#pragma unroll
            for (int ab = 0; ab < 2; ab++)
#pragma unroll
              for (int kf = 0; kf < 2; kf++) {
                const int row = h2 * 64 + sub * 32 + ab * 4 + permA;
                const int sk = (row & 3) | (((row >> 3) & 1) << 2);
                const int c = kf * 4 + g2;
                ak[sub][ab][kf] = *(const bf16x8*)&lsK[cur][row * 64 + ((c ^ sk) << 3)];
              }
          // V frags: [df][kv-quarter within half]
          bf16x8 vbf[4][2];
#pragma unroll
          for (int df = 0; df < 4; df++)
#pragma unroll
            for (int hh = 0; hh < 2; hh++) {
              const int row = df * 16 + fr;
              const int slot = h2 * 8 + (((hh * 4 + g2) ^ (row & 7)) & 7);
              vbf[df][hh] = *(const bf16x8*)&lsV[cur][row * 128 + (slot << 3)];
            }
          const int masked = (kvh == wb);
#pragma unroll
          for (int g = 0; g < 4; g++) {
            f32x4 sAB[2][2];
#pragma unroll
            for (int sub = 0; sub < 2; sub++)
#pragma unroll
              for (int ab = 0; ab < 2; ab++) {
                f32x4 s0 = (f32x4){0.f, 0.f, 0.f, 0.f};
                s0 = MFMA16(ak[sub][ab][0], bq[g][0], s0);
                s0 = MFMA16(ak[sub][ab][1], bq[g][1], s0);
                sAB[sub][ab] = s0;
              }
            float sv[16];
#pragma unroll
            for (int sub = 0; sub < 2; sub++)
#pragma unroll
              for (int r = 0; r < 4; r++) {
                sv[sub * 8 + r]     = sAB[sub][0][r];
                sv[sub * 8 + 4 + r] = sAB[sub][1][r];
              }
            if (masked) {
              const int q_abs = wb + g * 16 + fr;
#pragma unroll
              for (int sub = 0; sub < 2; sub++)
#pragma unroll
                for (int r = 0; r < 4; r++) {
                  if (kvh + sub * 32 + g2 * 8 + r     > q_abs) sv[sub * 8 + r]     = -1e30f;
                  if (kvh + sub * 32 + g2 * 8 + 4 + r > q_abs) sv[sub * 8 + 4 + r] = -1e30f;
                }
            }
            bf16_t pb[16];
#pragma unroll
            for (int jj = 0; jj < 16; jj++)
              pb[jj] = (bf16_t)exp2f(sv[jj]);   // no max; no VALU sum (l via MFMA)
            bf16x8 pa0, pa1;
#pragma unroll
            for (int jj = 0; jj < 8; jj++) { pa0[jj] = pb[jj]; pa1[jj] = pb[8 + jj]; }
#pragma unroll
            for (int df = 0; df < 4; df++) {
              o[g][df] = MFMA16(pa0, vbf[df][0], o[g][df]);
              o[g][df] = MFMA16(pa1, vbf[df][1], o[g][df]);
            }
            l_acc[g] = MFMA16(pa0, ones, l_acc[g]);
            l_acc[g] = MFMA16(pa1, ones, l_acc[g]);
          }
        }
      }
    }
    if (st + 1 < nst) WAIT_VM0_BAR();   // next tile landed; buffer safe to swap
  }

  // epilogue: 1/l is lane-local (l_acc rows == o rows); no shuffles
#pragma unroll
  for (int g = 0; g < 4; g++) {
#pragma unroll
    for (int r = 0; r < 4; r++) {
      const float iv = 1.f / l_acc[g][r];
      const int tok = b * SEQ + wb + g * 16 + g2 * 4 + r;
#pragma unroll
      for (int df = 0; df < 4; df++)
        attout[(size_t)tok * NX + h * HDIM + df * 16 + fr] = (bf16_t)(o[g][df][r] * iv);
    }
  }
}

// ---------------- launch ----------------
extern "C" void kernel_launch(void* const* d_in, const int* in_sizes, int n_in,
                              void* d_out, int out_size, void* d_ws, size_t ws_size,
                              hipStream_t stream) {
  const float* x      = (const float*)d_in[0];
  const float* w_attn = (const float*)d_in[1];
  const float* b_attn = (const float*)d_in[2];
  const float* w_proj = (const float*)d_in[3];
  const float* b_proj = (const float*)d_in[4];

  char* ws = (char*)d_ws;
  bf16_t* xb  = (bf16_t*)ws;                   // [0,16) MiB, reused as att
  bf16_t* qkv = (bf16_t*)(ws + (16u << 20));   // [16,64) MiB (V third = vt stripe)
  bf16_t* wab = (bf16_t*)(ws + (64u << 20));   // [64,70) MiB, dead after QKV GEMM
  bf16_t* wpb = (bf16_t*)(ws + (70u << 20));   // [70,72) MiB
  bf16_t* att = xb;

  k_prep<<<6144, 256, 0, stream>>>(x, xb, w_attn, wab, w_proj, wpb);
  k_gemm_qkv<<<dim3(NTOK / 128, (3 * NX) / 128), 256, 0, stream>>>(
      xb, wab, b_attn, qkv, NTOK, 3 * NX, NX);
  // xb and wab dead from here; V already transposed into the qkv stripe
  k_attn<<<BATCH * NHEAD * 8, 256, 0, stream>>>(qkv, att);
  k_gemm_bt<<<dim3(NTOK / 128, NX / 128), 256, 0, stream>>>(
      att, wpb, b_proj, (float*)d_out, NTOK, NX, NX);
}